// Round 25
// baseline (124.676 us; speedup 1.0000x reference)
//
#include <hip/hip_runtime.h>
#include <hip/hip_bf16.h>
#include <math.h>

#define DMODEL 512
#define DINNER 1024
#define DSTATE 16
#define SEQLEN 2048
#define NTOK   4096
#define CHUNK  64
#define NCHUNK (SEQLEN / CHUNK)  // 32

typedef __bf16 bf16x8 __attribute__((ext_vector_type(8)));
typedef float  f32x4  __attribute__((ext_vector_type(4)));

__device__ __forceinline__ float silu_f(float x) {
    return x / (1.0f + __expf(-x));
}

__device__ __forceinline__ float softplus_f(float x) {
    return fmaxf(x, 0.f) + __logf(1.0f + __expf(-fabsf(x)));
}

// swizzled LDS index (bf16 elems) for row r, 16B slot s (8 slots per 64-elem row)
__device__ __forceinline__ int swz(int r, int s) {
    return r * 64 + ((s ^ (r & 7)) << 3);
}

// async global->LDS 16B; LDS dest is wave-uniform base + lane*16
__device__ __forceinline__ void gload16(const void* g, void* l) {
    __builtin_amdgcn_global_load_lds(
        (const __attribute__((address_space(1))) void*)g,
        (__attribute__((address_space(3))) void*)l, 16, 0, 0);
}

// counted vmcnt wait (leaves N newest VMEM ops in flight) + scheduler fence
template<int N>
__device__ __forceinline__ void waitcnt_vm() {
    if constexpr (N == 0)      asm volatile("s_waitcnt vmcnt(0)" ::: "memory");
    else if constexpr (N == 3) asm volatile("s_waitcnt vmcnt(3)" ::: "memory");
    else if constexpr (N == 4) asm volatile("s_waitcnt vmcnt(4)" ::: "memory");
    else if constexpr (N == 6) asm volatile("s_waitcnt vmcnt(6)" ::: "memory");
    else                       asm volatile("s_waitcnt vmcnt(0)" ::: "memory");
    __builtin_amdgcn_sched_barrier(0);
}

__device__ __forceinline__ void cvt4(const float* src, __hip_bfloat16* dst) {
    float4 v = *reinterpret_cast<const float4*>(src);
    __hip_bfloat16 tmp[4] = {__float2bfloat16(v.x), __float2bfloat16(v.y),
                             __float2bfloat16(v.z), __float2bfloat16(v.w)};
    *reinterpret_cast<ushort4*>(dst) = *reinterpret_cast<const ushort4*>(tmp);
}

// ---------------------------------------------------------------------------
// bf16 MFMA GEMM, tile TBM x TBN, BK=64, 4 waves (2x2), gload_lds staging,
// DOUBLE-buffered LDS with COUNTED-vmcnt pipeline (T4):
//   {stage(t+1)->buf^1; vmcnt(NLD); s_barrier; MFMA(buf); lgkmcnt(0); s_barrier}
// Next tile's loads stay in flight through the MFMA phase (no vmcnt(0) drain).
// Row-major interleaved XCD swizzle (round-robin, load-balanced).
// MODE 0: fused conv(split-K2)+z triple path (x: P0 | P1 | z)
// MODE 2: delta+BC  MODE 3: plain  MODE 4: fused-weight per-tap
// ---------------------------------------------------------------------------
template<int MODE, int TBM, int TBN>
__global__ __launch_bounds__(256)
void mgemm(const __hip_bfloat16* __restrict__ A, int lda,
           const __hip_bfloat16* __restrict__ WT, int ldw,
           float* __restrict__ C0, __hip_bfloat16* __restrict__ Cb,
           __hip_bfloat16* __restrict__ Czb, int ldc,
           int K, const float* __restrict__ bias,
           const __hip_bfloat16* __restrict__ xc,
           const __hip_bfloat16* __restrict__ WT2, int ldw2,
           const __hip_bfloat16* __restrict__ zpage,
           const float* __restrict__ bB, const float* __restrict__ bC,
           float* __restrict__ BmO, float* __restrict__ CmO,
           __hip_bfloat16* __restrict__ Pb1)
{
    constexpr int MI = TBM / 32;
    constexpr int MJ = TBN / 32;
    constexpr int NLD = MI + MJ;          // gload16 issues per wave per tile
    __shared__ __align__(16) __hip_bfloat16 As[2 * TBM * 64];
    __shared__ __align__(16) __hip_bfloat16 Bs[2 * TBN * 64];

    // bijective XCD swizzle (all launches have nb % 8 == 0), row-major
    const int nb  = gridDim.x * gridDim.y;
    const int lin = blockIdx.y * gridDim.x + blockIdx.x;
    const int cpx = nb >> 3;
    const int sl  = (lin & 7) * cpx + (lin >> 3);
    const int bm  = (sl / gridDim.x) * TBM;
    const int bn  = (sl % gridDim.x) * TBN;

    if (MODE == 4) { A += blockIdx.z * 1024; Cb += blockIdx.z * 512; }

    const int  xsel = (MODE == 0) ? (bn >> 10) : 0;   // 0,1: conv halves; 2: z
    const bool zblk = (MODE == 0) && (xsel == 2);
    const int  bnb  = (MODE == 0) ? (bn & 1023) : bn;
    const __hip_bfloat16* Wp = zblk ? WT2 : WT;
    const int  ldwp = zblk ? ldw2 : ldw;
    const int  Keff = (MODE == 0 && zblk) ? DMODEL : K;
    const int  koff = (MODE == 0 && xsel == 1) ? 1024 : 0;

    const int tid  = threadIdx.x;
    const int wid  = tid >> 6, lane = tid & 63;
    const int wr   = (wid >> 1) * (TBM / 2), wc = (wid & 1) * (TBN / 2);
    const int llo  = lane & 15, lhi = lane >> 4;

    f32x4 acc[MI][MJ] = {};

    const int srow0 = wid * 8 + (lane >> 3);
    const int sphys = lane & 7;

    auto stage_tile = [&](int k0, int buf) {
        __hip_bfloat16* Ad = As + buf * (TBM * 64);
        __hip_bfloat16* Bd = Bs + buf * (TBN * 64);
#pragma unroll
        for (int q2 = 0; q2 < MI; ++q2) {
            int row  = q2 * 32 + srow0;
            int sdat = sphys ^ (row & 7);
            const __hip_bfloat16* srcA;
            if (MODE == 0 && !zblk) {
                int kg  = koff + k0;
                int kid = kg >> 9;
                int gr  = bm + row;
                int l2  = (gr & (SEQLEN - 1)) + kid - 1;
                srcA = ((unsigned)l2 < (unsigned)SEQLEN)
                     ? A + (size_t)(gr + kid - 1) * lda + (kg & 511) + sdat * 8
                     : zpage;
            } else {
                srcA = A + (size_t)(bm + row) * lda + k0 + sdat * 8;
            }
            gload16(srcA, &Ad[q2 * 2048 + wid * 512]);
        }
#pragma unroll
        for (int q2 = 0; q2 < MJ; ++q2) {
            int row  = q2 * 32 + srow0;
            int sdat = sphys ^ (row & 7);
            gload16(Wp + (size_t)(bnb + row) * ldwp + koff + k0 + sdat * 8,
                    &Bd[q2 * 2048 + wid * 512]);
        }
    };

    const int NT = Keff / 64;
    stage_tile(0, 0);
    for (int t = 0; t < NT; ++t) {
        if (t + 1 < NT) {
            stage_tile((t + 1) * 64, (t + 1) & 1);   // stays in flight over MFMA
            waitcnt_vm<NLD>();                        // tile t landed; t+1 in flight
        } else {
            waitcnt_vm<0>();
        }
        __builtin_amdgcn_s_barrier();                 // all waves' tile-t writes visible
        const __hip_bfloat16* Ab = As + (t & 1) * (TBM * 64);
        const __hip_bfloat16* Bb = Bs + (t & 1) * (TBN * 64);
#pragma unroll
        for (int kk = 0; kk < 2; ++kk) {
            bf16x8 af[MI], bv[MJ];
#pragma unroll
            for (int i = 0; i < MI; ++i)
                af[i] = *reinterpret_cast<const bf16x8*>(&Ab[swz(wr + i * 16 + llo, kk * 4 + lhi)]);
#pragma unroll
            for (int j = 0; j < MJ; ++j)
                bv[j] = *reinterpret_cast<const bf16x8*>(&Bb[swz(wc + j * 16 + llo, kk * 4 + lhi)]);
#pragma unroll
            for (int i = 0; i < MI; ++i)
#pragma unroll
                for (int j = 0; j < MJ; ++j)
                    acc[i][j] = __builtin_amdgcn_mfma_f32_16x16x32_bf16(af[i], bv[j], acc[i][j], 0, 0, 0);
        }
        asm volatile("s_waitcnt lgkmcnt(0)" ::: "memory");  // my ds_reads done
        __builtin_amdgcn_sched_barrier(0);
        __builtin_amdgcn_s_barrier();                 // safe to overwrite buf next iter
    }

#pragma unroll
    for (int i = 0; i < MI; ++i) {
#pragma unroll
        for (int q2 = 0; q2 < 4; ++q2) {
            int m = bm + wr + i * 16 + lhi * 4 + q2;
            float dec = 1.0f;
            if (MODE == 2)
                dec = __expf((float)((m & (SEQLEN - 1)) + 1) * -0.051293294f); // ln 0.95
#pragma unroll
            for (int j = 0; j < MJ; ++j) {
                int nrel = wc + j * 16 + llo;
                int n = bn + nrel;
                float v = acc[i][j][q2];
                if (MODE == 0) {
                    int col = bnb + nrel;
                    if (zblk) {
                        Czb[(size_t)m * DINNER + col] = __float2bfloat16(v);
                    } else {
                        __hip_bfloat16* P = xsel ? Pb1 : Cb;
                        P[(size_t)m * DINNER + col] = __float2bfloat16(v);
                    }
                } else if (MODE == 2) {
                    if (n < DINNER) {
                        float sp = softplus_f(v + bias[n]);
                        float xcv = __bfloat162float(xc[(size_t)m * DINNER + n]);
                        Cb[(size_t)m * DINNER + n] = __float2bfloat16(sp * xcv * dec);
                    } else {
                        int col = n - DINNER;
                        if (col < 16)
                            BmO[(size_t)m * DSTATE + col] = v + bB[col];
                        else if (col < 32)
                            CmO[(size_t)m * DSTATE + (col - 16)] = v + bC[col - 16];
                    }
                } else if (MODE == 4) {
                    Cb[(size_t)m * ldc + n] = __float2bfloat16(v);
                } else {
                    C0[(size_t)m * ldc + n] = v;
                }
            }
        }
    }
}

// combine split-K conv halves: xcb = bf16(silu(P0 + P1 + bias[n]))
__global__ __launch_bounds__(256)
void combine_k(const __hip_bfloat16* __restrict__ P0,
               const __hip_bfloat16* __restrict__ P1,
               const float* __restrict__ bias,
               __hip_bfloat16* __restrict__ xcb)
{
    int idx = blockIdx.x * 256 + threadIdx.x;
    size_t off = (size_t)idx * 4;
    int n = (int)(off & 1023);
    ushort4 a = *reinterpret_cast<const ushort4*>(&P0[off]);
    ushort4 b = *reinterpret_cast<const ushort4*>(&P1[off]);
    __hip_bfloat16 o[4];
#pragma unroll
    for (int j = 0; j < 4; ++j) {
        float va = __bfloat162float(((const __hip_bfloat16*)&a)[j]);
        float vb = __bfloat162float(((const __hip_bfloat16*)&b)[j]);
        o[j] = __float2bfloat16(silu_f(va + vb + bias[n + j]));
    }
    *reinterpret_cast<ushort4*>(&xcb[off]) = *reinterpret_cast<const ushort4*>(o);
}

// ---------------------------------------------------------------------------
// prep megakernel — one launch for all input/weight prep
// ---------------------------------------------------------------------------
__global__ __launch_bounds__(256)
void prep_k(const float* __restrict__ x, const float* __restrict__ w_in,
            const float* __restrict__ conv_k, const float* __restrict__ w_del,
            const float* __restrict__ w_B, const float* __restrict__ w_C,
            const float* __restrict__ w_out,
            __hip_bfloat16* __restrict__ xb, __hip_bfloat16* __restrict__ W1b,
            __hip_bfloat16* __restrict__ w2T, __hip_bfloat16* __restrict__ convT,
            __hip_bfloat16* __restrict__ wdelT, __hip_bfloat16* __restrict__ woutT,
            __hip_bfloat16* __restrict__ zpage)
{
    __shared__ float t[32][33];
    const int b = blockIdx.x, tid = threadIdx.x;
    if (b < 2048) {
        int idx = b * 256 + tid;
        int r = idx >> 7, c = (idx & 127) * 4;
        cvt4(x + (size_t)r * DMODEL + c, xb + (size_t)r * DMODEL + c);
    } else if (b < 2560) {
        int idx = (b - 2048) * 256 + tid;
        int r = idx >> 8, c = (idx & 255) * 4;
        cvt4(w_in + (size_t)r * (2 * DINNER) + c, W1b + (size_t)r * DINNER + c);
    } else if (b < 8704) {
        const float* in; __hip_bfloat16* outp; int R, ldin, ntx, local;
        if (b < 3072)      { local = b - 2560; in = w_in + DINNER; outp = w2T;   R = 512;  ldin = 2048; ntx = 32; }
        else if (b < 7168) { local = b - 3072; in = conv_k;        outp = convT; R = 4096; ldin = 1024; ntx = 32; }
        else if (b < 8192) { local = b - 7168; in = w_del;         outp = wdelT; R = 1024; ldin = 1024; ntx = 32; }
        else               { local = b - 8192; in = w_out;         outp = woutT; R = 1024; ldin = 512;  ntx = 16; }
        int bx = (local % ntx) * 32, by = (local / ntx) * 32;
        int tx = tid & 31, ty = tid >> 5;
#pragma unroll
        for (int q = 0; q < 4; ++q)
            t[ty + q * 8][tx] = in[(size_t)(by + ty + q * 8) * ldin + bx + tx];
        __syncthreads();
#pragma unroll
        for (int q = 0; q < 4; ++q)
            outp[(size_t)(bx + ty + q * 8) * R + by + tx] = __float2bfloat16(t[tx][ty + q * 8]);
    } else if (b < 8832) {
        int idx = (b - 8704) * 256 + tid;    // 0..32767
        int sel = idx >> 14;
        int rem = idx & 16383;
        int s = rem >> 10, k = rem & 1023;
        const float* src = sel ? w_C : w_B;
        wdelT[(size_t)(1024 + sel * 16 + s) * DINNER + k] =
            __float2bfloat16(src[(size_t)k * DSTATE + s]);
    } else {
        int local = b - 8832;
        ushort4 zero = {0, 0, 0, 0};
        if (local < 8) {
            int idx = local * 256 + tid;
            *reinterpret_cast<ushort4*>(&zpage[idx * 4]) = zero;
        } else {
            int idx = (local - 8) * 256 + tid;
            *reinterpret_cast<ushort4*>(&wdelT[(size_t)1056 * DINNER + idx * 4]) = zero;
        }
    }
}

// ---------------------------------------------------------------------------
// MFMA chunkS: per block (bc, n-block of 128): S[n][s] = sum_t w[t,n]*Bm[t,s]
// ---------------------------------------------------------------------------
__global__ __launch_bounds__(256)
void chunkS_k(const __hip_bfloat16* __restrict__ wb, const float* __restrict__ Bm,
              float* __restrict__ S)
{
    constexpr int LDW = 72;
    __shared__ __align__(16) __hip_bfloat16 wT[128 * LDW];
    __shared__ __align__(16) __hip_bfloat16 bT[16 * 80];
    const int bc = blockIdx.x, n0 = blockIdx.y * 128, t0 = bc * CHUNK;
    const int tid = threadIdx.x;
#pragma unroll
    for (int q = 0; q < 8; ++q) {
        int idx = tid + q * 256;
        int t = idx >> 5, n4 = (idx & 31) * 4;
        int key = ((n4 >> 2) & 7) << 3;
        int tx = t ^ key;
        ushort4 v = *reinterpret_cast<const ushort4*>(
            &wb[(size_t)(t0 + t) * DINNER + n0 + n4]);
        wT[(n4 + 0) * LDW + tx] = *(const __hip_bfloat16*)&v.x;
        wT[(n4 + 1) * LDW + tx] = *(const __hip_bfloat16*)&v.y;
        wT[(n4 + 2) * LDW + tx] = *(const __hip_bfloat16*)&v.z;
        wT[(n4 + 3) * LDW + tx] = *(const __hip_bfloat16*)&v.w;
    }
#pragma unroll
    for (int q = 0; q < 4; ++q) {
        int idx = tid + q * 256;
        int t = idx >> 4, s = idx & 15;
        bT[s * 80 + t] = __float2bfloat16(Bm[(size_t)(t0 + t) * DSTATE + s]);
    }
    __syncthreads();
    const int wid = tid >> 6, lane = tid & 63;
    const int llo = lane & 15, lhi = lane >> 4;
    f32x4 acc[2] = {};
#pragma unroll
    for (int kk = 0; kk < 2; ++kk) {
        bf16x8 bv = *reinterpret_cast<const bf16x8*>(&bT[llo * 80 + kk * 32 + lhi * 8]);
#pragma unroll
        for (int i = 0; i < 2; ++i) {
            int r = wid * 32 + i * 16 + llo;
            int kbase = (kk * 32 + lhi * 8) ^ (((r >> 2) & 7) << 3);
            bf16x8 af = *reinterpret_cast<const bf16x8*>(&wT[r * LDW + kbase]);
            acc[i] = __builtin_amdgcn_mfma_f32_16x16x32_bf16(af, bv, acc[i], 0, 0, 0);
        }
    }
#pragma unroll
    for (int i = 0; i < 2; ++i)
#pragma unroll
        for (int q = 0; q < 4; ++q) {
            int n = wid * 32 + i * 16 + lhi * 4 + q;
            S[((size_t)bc * DINNER + n0 + n) * DSTATE + llo] = acc[i][q];
        }
}

// exclusive prefix over chunks -> bf16 H
__global__ __launch_bounds__(256)
void hpre_k(const float* __restrict__ S, __hip_bfloat16* __restrict__ Hb)
{
    int idx = blockIdx.x * 256 + threadIdx.x;
    int b  = idx >> 14;
    int ns = idx & 16383;
    float acc = 0.f;
    for (int c = 0; c < NCHUNK; ++c) {
        size_t off = ((size_t)(b * NCHUNK + c)) * (DINNER * DSTATE) + ns;
        Hb[off] = __float2bfloat16(acc);
        acc += S[off];
    }
}

// ---------------------------------------------------------------------------
// MFMA intra-chunk: P = Cm@Bm^T (mask t<=l) -> bf16 LDS; Y = [P|Cm]@[w^T;H^T];
// g = Y * silu(z)
// ---------------------------------------------------------------------------
__global__ __launch_bounds__(256)
void intra_k(const __hip_bfloat16* __restrict__ wb,
             const float* __restrict__ Bm, const float* __restrict__ Cm,
             const __hip_bfloat16* __restrict__ Hb,
             const __hip_bfloat16* __restrict__ zb,
             __hip_bfloat16* __restrict__ gb)
{
    constexpr int LDP  = 104;
    constexpr int LDC  = 40;
    __shared__ __align__(16) __hip_bfloat16 csb[64 * LDC];
    __shared__ __align__(16) __hip_bfloat16 bsb[64 * LDC];
    __shared__ __align__(16) __hip_bfloat16 Pb [64 * LDP];
    __shared__ __align__(16) __hip_bfloat16 Wb [64 * LDP];

    const int bc = blockIdx.x;
    const int n0 = blockIdx.y * 64;
    const int t0 = bc * CHUNK;
    const int tid = threadIdx.x;
    const int wid = tid >> 6, lane = tid & 63;
    const int llo = lane & 15, lhi = lane >> 4;
    const int wr = (wid >> 1) * 32, wc = (wid & 1) * 32;
    const __hip_bfloat16 z16 = __float2bfloat16(0.f);

#pragma unroll
    for (int q = 0; q < 4; ++q) {
        int idx = tid + q * 256;
        int j = idx >> 4, s = idx & 15;
        __hip_bfloat16 cb = __float2bfloat16(Cm[(size_t)(t0 + j) * DSTATE + s]);
        csb[j * LDC + s]      = cb;
        csb[j * LDC + 16 + s] = z16;
        bsb[j * LDC + s]      = __float2bfloat16(Bm[(size_t)(t0 + j) * DSTATE + s]);
        bsb[j * LDC + 16 + s] = z16;
        Pb[j * LDP + 64 + s]  = cb;
        Pb[j * LDP + 80 + s]  = z16;
        Wb[j * LDP + 64 + s]  = Hb[((size_t)bc * DINNER + n0 + j) * DSTATE + s];
        Wb[j * LDP + 80 + s]  = z16;
    }
#pragma unroll
    for (int q = 0; q < 4; ++q) {
        int c = tid + q * 256;
        int t = c >> 4, c4 = (c & 15) * 4;
        ushort4 v = *reinterpret_cast<const ushort4*>(
            &wb[(size_t)(t0 + t) * DINNER + n0 + c4]);
        Wb[(c4 + 0) * LDP + t] = *(const __hip_bfloat16*)&v.x;
        Wb[(c4 + 1) * LDP + t] = *(const __hip_bfloat16*)&v.y;
        Wb[(c4 + 2) * LDP + t] = *(const __hip_bfloat16*)&v.z;
        Wb[(c4 + 3) * LDP + t] = *(const __hip_bfloat16*)&v.w;
    }
    __syncthreads();

    {
        f32x4 pacc[2][2] = {};
        bf16x8 ap[2], bp[2];
#pragma unroll
        for (int i = 0; i < 2; ++i)
            ap[i] = *reinterpret_cast<const bf16x8*>(&csb[(wr + i * 16 + llo) * LDC + lhi * 8]);
#pragma unroll
        for (int j = 0; j < 2; ++j)
            bp[j] = *reinterpret_cast<const bf16x8*>(&bsb[(wc + j * 16 + llo) * LDC + lhi * 8]);
#pragma unroll
        for (int i = 0; i < 2; ++i)
#pragma unroll
            for (int j = 0; j < 2; ++j)
                pacc[i][j] = __builtin_amdgcn_mfma_f32_16x16x32_bf16(ap[i], bp[j], pacc[i][j], 0, 0, 0);
#pragma unroll
        for (int i = 0; i < 2; ++i)
#pragma unroll
            for (int q = 0; q < 4; ++q) {
                int l = wr + i * 16 + lhi * 4 + q;
#pragma unroll
                for (int j = 0; j < 2; ++j) {
                    int t = wc + j * 16 + llo;
                    float pv = (t <= l) ? pacc[i][j][q] : 0.f;
                    Pb[l * LDP + t] = __float2bfloat16(pv);
                }
            }
    }
    __syncthreads();

    f32x4 yacc[2][2] = {};
#pragma unroll
    for (int k0 = 0; k0 < 3; ++k0) {
        bf16x8 af[2], bv[2];
#pragma unroll
        for (int i = 0; i < 2; ++i)
            af[i] = *reinterpret_cast<const bf16x8*>(&Pb[(wr + i * 16 + llo) * LDP + k0 * 32 + lhi * 8]);
#pragma unroll
        for (int j = 0; j < 2; ++j)
            bv[j] = *reinterpret_cast<const bf16x8*>(&Wb[(wc + j * 16 + llo) * LDP + k0 * 32 + lhi * 8]);
#pragma unroll
        for (int i = 0; i < 2; ++i)
#pragma unroll
            for (int j = 0; j < 2; ++j)
                yacc[i][j] = __builtin_amdgcn_mfma_f32_16x16x32_bf16(af[i], bv[j], yacc[i][j], 0, 0, 0);
    }

#pragma unroll
    for (int i = 0; i < 2; ++i)
#pragma unroll
        for (int q = 0; q < 4; ++q) {
            int l = wr + i * 16 + lhi * 4 + q;
            int token = t0 + l;
#pragma unroll
            for (int j = 0; j < 2; ++j) {
                int n = wc + j * 16 + llo;
                float z = __bfloat162float(zb[(size_t)token * DINNER + n0 + n]);
                gb[(size_t)token * DINNER + n0 + n] =
                    __float2bfloat16(yacc[i][j][q] * silu_f(z));
            }
        }
}

extern "C" void kernel_launch(void* const* d_in, const int* in_sizes, int n_in,
                              void* d_out, int out_size, void* d_ws, size_t ws_size,
                              hipStream_t stream) {
    const float* x      = (const float*)d_in[0];
    const float* w_in   = (const float*)d_in[1];
    const float* conv_k = (const float*)d_in[2];
    const float* conv_b = (const float*)d_in[3];
    const float* w_del  = (const float*)d_in[4];
    const float* b_del  = (const float*)d_in[5];
    const float* w_B    = (const float*)d_in[6];
    const float* b_B    = (const float*)d_in[7];
    const float* w_C    = (const float*)d_in[8];
    const float* b_C    = (const float*)d_in[9];
    const float* w_out  = (const float*)d_in[11];
    float* out = (float*)d_out;

    // f32 region
    float* Bm    = (float*)d_ws;
    float* Cm    = Bm + (size_t)NTOK * DSTATE;
    float* S     = Cm + (size_t)NTOK * DSTATE;            // 1M f32
    // bf16 region
    __hip_bfloat16* Hb    = (__hip_bfloat16*)(S + (size_t)2 * NCHUNK * DINNER * DSTATE);
    __hip_bfloat16* xb    = Hb    + (size_t)2 * NCHUNK * DINNER * DSTATE;  // 1M elems
    __hip_bfloat16* xcb   = xb    + (size_t)NTOK * DMODEL;        // 4M elems
    __hip_bfloat16* zb    = xcb   + (size_t)NTOK * DINNER;        // 4M
    __hip_bfloat16* gb    = zb    + (size_t)NTOK * DINNER;        // 4M
    __hip_bfloat16* wbufb = gb    + (size_t)NTOK * DINNER;        // 4M
    __hip_bfloat16* W1b   = wbufb + (size_t)NTOK * DINNER;        // 0.5M
    __hip_bfloat16* w2T   = W1b   + (size_t)DMODEL * DINNER;      // 0.5M
    __hip_bfloat16* convT = w2T   + (size_t)DINNER * DMODEL;      // 4M
    __hip_bfloat16* wdelT = convT + (size_t)4 * DINNER * DINNER;  // 1088 x 1024
    __hip_bfloat16* woutT = wdelT + (size_t)1088 * DINNER;        // 0.5M
    __hip_bfloat16* FT    = woutT + (size_t)DINNER * DMODEL;      // 2M (1024 x 2048)
    __hip_bfloat16* zpage = FT    + (size_t)DINNER * 2048;        // 8K elems
    __hip_bfloat16* P0    = zpage + 8192;                         // 4M elems
    __hip_bfloat16* P1    = P0    + (size_t)NTOK * DINNER;        // 4M elems

    // one-launch prep: cvts + transposes + bcw + zero fills
    prep_k<<<8872, 256, 0, stream>>>(x, w_in, conv_k, w_del, w_B, w_C, w_out,
                                     xb, W1b, w2T, convT, wdelT, woutT, zpage);

    // fused conv weights: FT[o][tap*512 + dm] = (W1 @ K_tap)[dm][o], row stride 2048
    mgemm<4, 64, 64><<<dim3(DMODEL / 64, DINNER / 64, 4), 256, 0, stream>>>(
        convT, 4 * DINNER, W1b, DINNER, nullptr, FT, nullptr, 4 * DMODEL, DINNER,
        nullptr, nullptr, nullptr, 0, zpage, nullptr, nullptr, nullptr, nullptr, nullptr);
    // fused conv(split-K2)+z: bn<1024 -> P0 (taps 0-1); <2048 -> P1 (taps 2-3);
    //   else -> zb (K=512). tile 128x64, grid (48,32)=1536 (R21-best shape)
    mgemm<0, 128, 64><<<dim3(48, NTOK / 128), 256, 0, stream>>>(
        xb, DMODEL, FT, 4 * DMODEL, nullptr, P0, zb, DINNER, 1024,
        nullptr, nullptr, w2T, DMODEL, zpage, nullptr, nullptr, nullptr, nullptr, P1);
    // combine halves: xcb = bf16(silu(P0+P1+conv_b))
    combine_k<<<NTOK * DINNER / 1024, 256, 0, stream>>>(P0, P1, conv_b, xcb);
    // delta + B/C fused: N=1088, tile 64x64, grid (17,64)=1088 blocks (%8 ok)
    mgemm<2, 64, 64><<<dim3(1088 / 64, NTOK / 64), 256, 0, stream>>>(
        xcb, DINNER, wdelT, DINNER, nullptr, wbufb, nullptr, DINNER, DINNER,
        b_del, xcb, nullptr, 0, zpage, b_B, b_C, Bm, Cm, nullptr);
    // scan
    chunkS_k<<<dim3(2 * NCHUNK, DINNER / 128), 256, 0, stream>>>(wbufb, Bm, S);
    hpre_k<<<dim3(2 * DINNER * DSTATE / 256), 256, 0, stream>>>(S, Hb);
    intra_k<<<dim3(2 * NCHUNK, DINNER / 64), 256, 0, stream>>>(wbufb, Bm, Cm, Hb, zb, gb);
    // out = g @ w_out  (tile 64x32, grid (16,64)=1024 blocks)
    mgemm<3, 64, 32><<<dim3(DMODEL / 32, NTOK / 64), 256, 0, stream>>>(
        gb, DINNER, woutT, DINNER, out, nullptr, nullptr, DMODEL, DINNER,
        nullptr, nullptr, nullptr, 0, zpage, nullptr, nullptr, nullptr, nullptr, nullptr);
}

// Round 26
// 113.794 us; speedup vs baseline: 1.0956x; 1.0956x over previous
//
#include <hip/hip_runtime.h>
#include <hip/hip_bf16.h>
#include <math.h>

#define DMODEL 512
#define DINNER 1024
#define DSTATE 16
#define SEQLEN 2048
#define NTOK   4096
#define CHUNK  64
#define NCHUNK (SEQLEN / CHUNK)  // 32

typedef __bf16 bf16x8 __attribute__((ext_vector_type(8)));
typedef float  f32x4  __attribute__((ext_vector_type(4)));

__device__ __forceinline__ float silu_f(float x) {
    return x / (1.0f + __expf(-x));
}

// fast softplus: abs err ~1e-7, negligible at bf16 output precision
__device__ __forceinline__ float softplus_f(float x) {
    return fmaxf(x, 0.f) + __logf(1.0f + __expf(-fabsf(x)));
}

// swizzled LDS index (bf16 elems) for row r, 16B slot s (8 slots per 64-elem row)
__device__ __forceinline__ int swz(int r, int s) {
    return r * 64 + ((s ^ (r & 7)) << 3);
}

// async global->LDS 16B; LDS dest is wave-uniform base + lane*16
__device__ __forceinline__ void gload16(const void* g, void* l) {
    __builtin_amdgcn_global_load_lds(
        (const __attribute__((address_space(1))) void*)g,
        (__attribute__((address_space(3))) void*)l, 16, 0, 0);
}

__device__ __forceinline__ void cvt4(const float* src, __hip_bfloat16* dst) {
    float4 v = *reinterpret_cast<const float4*>(src);
    __hip_bfloat16 tmp[4] = {__float2bfloat16(v.x), __float2bfloat16(v.y),
                             __float2bfloat16(v.z), __float2bfloat16(v.w)};
    *reinterpret_cast<ushort4*>(dst) = *reinterpret_cast<const ushort4*>(tmp);
}

// ---------------------------------------------------------------------------
// bf16 MFMA GEMM, tile TBM x TBN, BK=64, 4 waves (2x2), gload_lds staging,
// single-buffer LDS, 2-barrier loop: {stage(t); bar; MFMA(t); bar}.
// Row-major interleaved XCD swizzle (round-robin -> load-balanced).
// MODE 0: fused conv(split-K2)+z triple path, grid x blocks of 1024 cols:
//         bn<1024:       conv half 0 (taps 0-1, K=1024) -> P0 bf16 raw partial
//         bn in [1024,2048): conv half 1 (taps 2-3)     -> P1 bf16 raw partial
//         else:          z (w2T, K=512) -> Czb bf16
// MODE 2: delta+BC — n<1024: softplus(acc+bias[n])*xc[m,n]*0.95^(l+1) -> Cb bf16;
//         n in [1024,1040): Bm = acc+bB ; [1040,1056): Cm = acc+bC ; else drop
// MODE 3: plain — C0 = acc (f32)
// MODE 4: fused-weight GEMM — per-tap (blockIdx.z), bf16 store at ldc stride
// ---------------------------------------------------------------------------
template<int MODE, int TBM, int TBN>
__global__ __launch_bounds__(256)
void mgemm(const __hip_bfloat16* __restrict__ A, int lda,
           const __hip_bfloat16* __restrict__ WT, int ldw,
           float* __restrict__ C0, __hip_bfloat16* __restrict__ Cb,
           __hip_bfloat16* __restrict__ Czb, int ldc,
           int K, const float* __restrict__ bias,
           const __hip_bfloat16* __restrict__ xc,
           const __hip_bfloat16* __restrict__ WT2, int ldw2,
           const __hip_bfloat16* __restrict__ zpage,
           const float* __restrict__ bB, const float* __restrict__ bC,
           float* __restrict__ BmO, float* __restrict__ CmO,
           __hip_bfloat16* __restrict__ Pb1)
{
    constexpr int MI = TBM / 32;
    constexpr int MJ = TBN / 32;
    __shared__ __align__(16) __hip_bfloat16 As[TBM * 64];
    __shared__ __align__(16) __hip_bfloat16 Bs[TBN * 64];

    // bijective XCD swizzle (all launches have nb % 8 == 0), row-major
    const int nb  = gridDim.x * gridDim.y;
    const int lin = blockIdx.y * gridDim.x + blockIdx.x;
    const int cpx = nb >> 3;
    const int sl  = (lin & 7) * cpx + (lin >> 3);
    const int bm  = (sl / gridDim.x) * TBM;
    const int bn  = (sl % gridDim.x) * TBN;

    if (MODE == 4) { A += blockIdx.z * 1024; Cb += blockIdx.z * 512; }

    const int  xsel = (MODE == 0) ? (bn >> 10) : 0;   // 0,1: conv halves; 2: z
    const bool zblk = (MODE == 0) && (xsel == 2);
    const int  bnb  = (MODE == 0) ? (bn & 1023) : bn;
    const __hip_bfloat16* Wp = zblk ? WT2 : WT;
    const int  ldwp = zblk ? ldw2 : ldw;
    const int  Keff = (MODE == 0 && zblk) ? DMODEL : K;
    const int  koff = (MODE == 0 && xsel == 1) ? 1024 : 0;

    const int tid  = threadIdx.x;
    const int wid  = tid >> 6, lane = tid & 63;
    const int wr   = (wid >> 1) * (TBM / 2), wc = (wid & 1) * (TBN / 2);
    const int llo  = lane & 15, lhi = lane >> 4;

    f32x4 acc[MI][MJ] = {};

    const int srow0 = wid * 8 + (lane >> 3);
    const int sphys = lane & 7;

    auto stage_tile = [&](int k0) {
#pragma unroll
        for (int q2 = 0; q2 < MI; ++q2) {
            int row  = q2 * 32 + srow0;
            int sdat = sphys ^ (row & 7);
            const __hip_bfloat16* srcA;
            if (MODE == 0 && !zblk) {
                int kg  = koff + k0;
                int kid = kg >> 9;
                int gr  = bm + row;
                int l2  = (gr & (SEQLEN - 1)) + kid - 1;
                srcA = ((unsigned)l2 < (unsigned)SEQLEN)
                     ? A + (size_t)(gr + kid - 1) * lda + (kg & 511) + sdat * 8
                     : zpage;
            } else {
                srcA = A + (size_t)(bm + row) * lda + k0 + sdat * 8;
            }
            gload16(srcA, &As[q2 * 2048 + wid * 512]);
        }
#pragma unroll
        for (int q2 = 0; q2 < MJ; ++q2) {
            int row  = q2 * 32 + srow0;
            int sdat = sphys ^ (row & 7);
            gload16(Wp + (size_t)(bnb + row) * ldwp + koff + k0 + sdat * 8,
                    &Bs[q2 * 2048 + wid * 512]);
        }
    };

    const int NT = Keff / 64;
    for (int t = 0; t < NT; ++t) {
        stage_tile(t * 64);
        __syncthreads();
#pragma unroll
        for (int kk = 0; kk < 2; ++kk) {
            bf16x8 af[MI], bv[MJ];
#pragma unroll
            for (int i = 0; i < MI; ++i)
                af[i] = *reinterpret_cast<const bf16x8*>(&As[swz(wr + i * 16 + llo, kk * 4 + lhi)]);
#pragma unroll
            for (int j = 0; j < MJ; ++j)
                bv[j] = *reinterpret_cast<const bf16x8*>(&Bs[swz(wc + j * 16 + llo, kk * 4 + lhi)]);
#pragma unroll
            for (int i = 0; i < MI; ++i)
#pragma unroll
                for (int j = 0; j < MJ; ++j)
                    acc[i][j] = __builtin_amdgcn_mfma_f32_16x16x32_bf16(af[i], bv[j], acc[i][j], 0, 0, 0);
        }
        __syncthreads();
    }

#pragma unroll
    for (int i = 0; i < MI; ++i) {
#pragma unroll
        for (int q2 = 0; q2 < 4; ++q2) {
            int m = bm + wr + i * 16 + lhi * 4 + q2;
            float dec = 1.0f;
            if (MODE == 2)
                dec = __expf((float)((m & (SEQLEN - 1)) + 1) * -0.051293294f); // ln 0.95
#pragma unroll
            for (int j = 0; j < MJ; ++j) {
                int nrel = wc + j * 16 + llo;
                int n = bn + nrel;
                float v = acc[i][j][q2];
                if (MODE == 0) {
                    int col = bnb + nrel;
                    if (zblk) {
                        Czb[(size_t)m * DINNER + col] = __float2bfloat16(v);
                    } else {
                        __hip_bfloat16* P = xsel ? Pb1 : Cb;
                        P[(size_t)m * DINNER + col] = __float2bfloat16(v);
                    }
                } else if (MODE == 2) {
                    if (n < DINNER) {
                        float sp = softplus_f(v + bias[n]);
                        float xcv = __bfloat162float(xc[(size_t)m * DINNER + n]);
                        Cb[(size_t)m * DINNER + n] = __float2bfloat16(sp * xcv * dec);
                    } else {
                        int col = n - DINNER;
                        if (col < 16)
                            BmO[(size_t)m * DSTATE + col] = v + bB[col];
                        else if (col < 32)
                            CmO[(size_t)m * DSTATE + (col - 16)] = v + bC[col - 16];
                    }
                } else if (MODE == 4) {
                    Cb[(size_t)m * ldc + n] = __float2bfloat16(v);
                } else {
                    C0[(size_t)m * ldc + n] = v;
                }
            }
        }
    }
}

// combine split-K conv halves: xcb = bf16(silu(P0 + P1 + bias[n]))
__global__ __launch_bounds__(256)
void combine_k(const __hip_bfloat16* __restrict__ P0,
               const __hip_bfloat16* __restrict__ P1,
               const float* __restrict__ bias,
               __hip_bfloat16* __restrict__ xcb)
{
    int idx = blockIdx.x * 256 + threadIdx.x;
    size_t off = (size_t)idx * 4;
    int n = (int)(off & 1023);
    ushort4 a = *reinterpret_cast<const ushort4*>(&P0[off]);
    ushort4 b = *reinterpret_cast<const ushort4*>(&P1[off]);
    __hip_bfloat16 o[4];
#pragma unroll
    for (int j = 0; j < 4; ++j) {
        float va = __bfloat162float(((const __hip_bfloat16*)&a)[j]);
        float vb = __bfloat162float(((const __hip_bfloat16*)&b)[j]);
        o[j] = __float2bfloat16(silu_f(va + vb + bias[n + j]));
    }
    *reinterpret_cast<ushort4*>(&xcb[off]) = *reinterpret_cast<const ushort4*>(o);
}

// ---------------------------------------------------------------------------
// prep megakernel — one launch for all input/weight prep
// ---------------------------------------------------------------------------
__global__ __launch_bounds__(256)
void prep_k(const float* __restrict__ x, const float* __restrict__ w_in,
            const float* __restrict__ conv_k, const float* __restrict__ w_del,
            const float* __restrict__ w_B, const float* __restrict__ w_C,
            const float* __restrict__ w_out,
            __hip_bfloat16* __restrict__ xb, __hip_bfloat16* __restrict__ W1b,
            __hip_bfloat16* __restrict__ w2T, __hip_bfloat16* __restrict__ convT,
            __hip_bfloat16* __restrict__ wdelT, __hip_bfloat16* __restrict__ woutT,
            __hip_bfloat16* __restrict__ zpage)
{
    __shared__ float t[32][33];
    const int b = blockIdx.x, tid = threadIdx.x;
    if (b < 2048) {
        int idx = b * 256 + tid;
        int r = idx >> 7, c = (idx & 127) * 4;
        cvt4(x + (size_t)r * DMODEL + c, xb + (size_t)r * DMODEL + c);
    } else if (b < 2560) {
        int idx = (b - 2048) * 256 + tid;
        int r = idx >> 8, c = (idx & 255) * 4;
        cvt4(w_in + (size_t)r * (2 * DINNER) + c, W1b + (size_t)r * DINNER + c);
    } else if (b < 8704) {
        const float* in; __hip_bfloat16* outp; int R, ldin, ntx, local;
        if (b < 3072)      { local = b - 2560; in = w_in + DINNER; outp = w2T;   R = 512;  ldin = 2048; ntx = 32; }
        else if (b < 7168) { local = b - 3072; in = conv_k;        outp = convT; R = 4096; ldin = 1024; ntx = 32; }
        else if (b < 8192) { local = b - 7168; in = w_del;         outp = wdelT; R = 1024; ldin = 1024; ntx = 32; }
        else               { local = b - 8192; in = w_out;         outp = woutT; R = 1024; ldin = 512;  ntx = 16; }
        int bx = (local % ntx) * 32, by = (local / ntx) * 32;
        int tx = tid & 31, ty = tid >> 5;
#pragma unroll
        for (int q = 0; q < 4; ++q)
            t[ty + q * 8][tx] = in[(size_t)(by + ty + q * 8) * ldin + bx + tx];
        __syncthreads();
#pragma unroll
        for (int q = 0; q < 4; ++q)
            outp[(size_t)(bx + ty + q * 8) * R + by + tx] = __float2bfloat16(t[tx][ty + q * 8]);
    } else if (b < 8832) {
        int idx = (b - 8704) * 256 + tid;    // 0..32767
        int sel = idx >> 14;
        int rem = idx & 16383;
        int s = rem >> 10, k = rem & 1023;
        const float* src = sel ? w_C : w_B;
        wdelT[(size_t)(1024 + sel * 16 + s) * DINNER + k] =
            __float2bfloat16(src[(size_t)k * DSTATE + s]);
    } else {
        int local = b - 8832;
        ushort4 zero = {0, 0, 0, 0};
        if (local < 8) {
            int idx = local * 256 + tid;
            *reinterpret_cast<ushort4*>(&zpage[idx * 4]) = zero;
        } else {
            int idx = (local - 8) * 256 + tid;
            *reinterpret_cast<ushort4*>(&wdelT[(size_t)1056 * DINNER + idx * 4]) = zero;
        }
    }
}

// ---------------------------------------------------------------------------
// MFMA chunkS: per block (bc, n-block of 128): S[n][s] = sum_t w[t,n]*Bm[t,s]
// ---------------------------------------------------------------------------
__global__ __launch_bounds__(256)
void chunkS_k(const __hip_bfloat16* __restrict__ wb, const float* __restrict__ Bm,
              float* __restrict__ S)
{
    constexpr int LDW = 72;
    __shared__ __align__(16) __hip_bfloat16 wT[128 * LDW];
    __shared__ __align__(16) __hip_bfloat16 bT[16 * 80];
    const int bc = blockIdx.x, n0 = blockIdx.y * 128, t0 = bc * CHUNK;
    const int tid = threadIdx.x;
#pragma unroll
    for (int q = 0; q < 8; ++q) {
        int idx = tid + q * 256;
        int t = idx >> 5, n4 = (idx & 31) * 4;
        int key = ((n4 >> 2) & 7) << 3;
        int tx = t ^ key;
        ushort4 v = *reinterpret_cast<const ushort4*>(
            &wb[(size_t)(t0 + t) * DINNER + n0 + n4]);
        wT[(n4 + 0) * LDW + tx] = *(const __hip_bfloat16*)&v.x;
        wT[(n4 + 1) * LDW + tx] = *(const __hip_bfloat16*)&v.y;
        wT[(n4 + 2) * LDW + tx] = *(const __hip_bfloat16*)&v.z;
        wT[(n4 + 3) * LDW + tx] = *(const __hip_bfloat16*)&v.w;
    }
#pragma unroll
    for (int q = 0; q < 4; ++q) {
        int idx = tid + q * 256;
        int t = idx >> 4, s = idx & 15;
        bT[s * 80 + t] = __float2bfloat16(Bm[(size_t)(t0 + t) * DSTATE + s]);
    }
    __syncthreads();
    const int wid = tid >> 6, lane = tid & 63;
    const int llo = lane & 15, lhi = lane >> 4;
    f32x4 acc[2] = {};
#pragma unroll
    for (int kk = 0; kk < 2; ++kk) {
        bf16x8 bv = *reinterpret_cast<const bf16x8*>(&bT[llo * 80 + kk * 32 + lhi * 8]);
#pragma unroll
        for (int i = 0; i < 2; ++i) {
            int r = wid * 32 + i * 16 + llo;
            int kbase = (kk * 32 + lhi * 8) ^ (((r >> 2) & 7) << 3);
            bf16x8 af = *reinterpret_cast<const bf16x8*>(&wT[r * LDW + kbase]);
            acc[i] = __builtin_amdgcn_mfma_f32_16x16x32_bf16(af, bv, acc[i], 0, 0, 0);
        }
    }
#pragma unroll
    for (int i = 0; i < 2; ++i)
#pragma unroll
        for (int q = 0; q < 4; ++q) {
            int n = wid * 32 + i * 16 + lhi * 4 + q;
            S[((size_t)bc * DINNER + n0 + n) * DSTATE + llo] = acc[i][q];
        }
}

// exclusive prefix over chunks -> bf16 H
__global__ __launch_bounds__(256)
void hpre_k(const float* __restrict__ S, __hip_bfloat16* __restrict__ Hb)
{
    int idx = blockIdx.x * 256 + threadIdx.x;
    int b  = idx >> 14;
    int ns = idx & 16383;
    float acc = 0.f;
    for (int c = 0; c < NCHUNK; ++c) {
        size_t off = ((size_t)(b * NCHUNK + c)) * (DINNER * DSTATE) + ns;
        Hb[off] = __float2bfloat16(acc);
        acc += S[off];
    }
}

// ---------------------------------------------------------------------------
// MFMA intra-chunk: P = Cm@Bm^T (mask t<=l) -> bf16 LDS; Y = [P|Cm]@[w^T;H^T];
// g = Y * silu(z)
// ---------------------------------------------------------------------------
__global__ __launch_bounds__(256)
void intra_k(const __hip_bfloat16* __restrict__ wb,
             const float* __restrict__ Bm, const float* __restrict__ Cm,
             const __hip_bfloat16* __restrict__ Hb,
             const __hip_bfloat16* __restrict__ zb,
             __hip_bfloat16* __restrict__ gb)
{
    constexpr int LDP  = 104;
    constexpr int LDC  = 40;
    __shared__ __align__(16) __hip_bfloat16 csb[64 * LDC];
    __shared__ __align__(16) __hip_bfloat16 bsb[64 * LDC];
    __shared__ __align__(16) __hip_bfloat16 Pb [64 * LDP];
    __shared__ __align__(16) __hip_bfloat16 Wb [64 * LDP];

    const int bc = blockIdx.x;
    const int n0 = blockIdx.y * 64;
    const int t0 = bc * CHUNK;
    const int tid = threadIdx.x;
    const int wid = tid >> 6, lane = tid & 63;
    const int llo = lane & 15, lhi = lane >> 4;
    const int wr = (wid >> 1) * 32, wc = (wid & 1) * 32;
    const __hip_bfloat16 z16 = __float2bfloat16(0.f);

#pragma unroll
    for (int q = 0; q < 4; ++q) {
        int idx = tid + q * 256;
        int j = idx >> 4, s = idx & 15;
        __hip_bfloat16 cb = __float2bfloat16(Cm[(size_t)(t0 + j) * DSTATE + s]);
        csb[j * LDC + s]      = cb;
        csb[j * LDC + 16 + s] = z16;
        bsb[j * LDC + s]      = __float2bfloat16(Bm[(size_t)(t0 + j) * DSTATE + s]);
        bsb[j * LDC + 16 + s] = z16;
        Pb[j * LDP + 64 + s]  = cb;
        Pb[j * LDP + 80 + s]  = z16;
        Wb[j * LDP + 64 + s]  = Hb[((size_t)bc * DINNER + n0 + j) * DSTATE + s];
        Wb[j * LDP + 80 + s]  = z16;
    }
#pragma unroll
    for (int q = 0; q < 4; ++q) {
        int c = tid + q * 256;
        int t = c >> 4, c4 = (c & 15) * 4;
        ushort4 v = *reinterpret_cast<const ushort4*>(
            &wb[(size_t)(t0 + t) * DINNER + n0 + c4]);
        Wb[(c4 + 0) * LDP + t] = *(const __hip_bfloat16*)&v.x;
        Wb[(c4 + 1) * LDP + t] = *(const __hip_bfloat16*)&v.y;
        Wb[(c4 + 2) * LDP + t] = *(const __hip_bfloat16*)&v.z;
        Wb[(c4 + 3) * LDP + t] = *(const __hip_bfloat16*)&v.w;
    }
    __syncthreads();

    {
        f32x4 pacc[2][2] = {};
        bf16x8 ap[2], bp[2];
#pragma unroll
        for (int i = 0; i < 2; ++i)
            ap[i] = *reinterpret_cast<const bf16x8*>(&csb[(wr + i * 16 + llo) * LDC + lhi * 8]);
#pragma unroll
        for (int j = 0; j < 2; ++j)
            bp[j] = *reinterpret_cast<const bf16x8*>(&bsb[(wc + j * 16 + llo) * LDC + lhi * 8]);
#pragma unroll
        for (int i = 0; i < 2; ++i)
#pragma unroll
            for (int j = 0; j < 2; ++j)
                pacc[i][j] = __builtin_amdgcn_mfma_f32_16x16x32_bf16(ap[i], bp[j], pacc[i][j], 0, 0, 0);
#pragma unroll
        for (int i = 0; i < 2; ++i)
#pragma unroll
            for (int q = 0; q < 4; ++q) {
                int l = wr + i * 16 + lhi * 4 + q;
#pragma unroll
                for (int j = 0; j < 2; ++j) {
                    int t = wc + j * 16 + llo;
                    float pv = (t <= l) ? pacc[i][j][q] : 0.f;
                    Pb[l * LDP + t] = __float2bfloat16(pv);
                }
            }
    }
    __syncthreads();

    f32x4 yacc[2][2] = {};
#pragma unroll
    for (int k0 = 0; k0 < 3; ++k0) {
        bf16x8 af[2], bv[2];
#pragma unroll
        for (int i = 0; i < 2; ++i)
            af[i] = *reinterpret_cast<const bf16x8*>(&Pb[(wr + i * 16 + llo) * LDP + k0 * 32 + lhi * 8]);
#pragma unroll
        for (int j = 0; j < 2; ++j)
            bv[j] = *reinterpret_cast<const bf16x8*>(&Wb[(wc + j * 16 + llo) * LDP + k0 * 32 + lhi * 8]);
#pragma unroll
        for (int i = 0; i < 2; ++i)
#pragma unroll
            for (int j = 0; j < 2; ++j)
                yacc[i][j] = __builtin_amdgcn_mfma_f32_16x16x32_bf16(af[i], bv[j], yacc[i][j], 0, 0, 0);
    }

#pragma unroll
    for (int i = 0; i < 2; ++i)
#pragma unroll
        for (int q = 0; q < 4; ++q) {
            int l = wr + i * 16 + lhi * 4 + q;
            int token = t0 + l;
#pragma unroll
            for (int j = 0; j < 2; ++j) {
                int n = wc + j * 16 + llo;
                float z = __bfloat162float(zb[(size_t)token * DINNER + n0 + n]);
                gb[(size_t)token * DINNER + n0 + n] =
                    __float2bfloat16(yacc[i][j][q] * silu_f(z));
            }
        }
}

extern "C" void kernel_launch(void* const* d_in, const int* in_sizes, int n_in,
                              void* d_out, int out_size, void* d_ws, size_t ws_size,
                              hipStream_t stream) {
    const float* x      = (const float*)d_in[0];
    const float* w_in   = (const float*)d_in[1];
    const float* conv_k = (const float*)d_in[2];
    const float* conv_b = (const float*)d_in[3];
    const float* w_del  = (const float*)d_in[4];
    const float* b_del  = (const float*)d_in[5];
    const float* w_B    = (const float*)d_in[6];
    const float* b_B    = (const float*)d_in[7];
    const float* w_C    = (const float*)d_in[8];
    const float* b_C    = (const float*)d_in[9];
    const float* w_out  = (const float*)d_in[11];
    float* out = (float*)d_out;

    // f32 region
    float* Bm    = (float*)d_ws;
    float* Cm    = Bm + (size_t)NTOK * DSTATE;
    float* S     = Cm + (size_t)NTOK * DSTATE;            // 1M f32
    // bf16 region
    __hip_bfloat16* Hb    = (__hip_bfloat16*)(S + (size_t)2 * NCHUNK * DINNER * DSTATE);
    __hip_bfloat16* xb    = Hb    + (size_t)2 * NCHUNK * DINNER * DSTATE;  // 1M elems
    __hip_bfloat16* xcb   = xb    + (size_t)NTOK * DMODEL;        // 4M elems
    __hip_bfloat16* zb    = xcb   + (size_t)NTOK * DINNER;        // 4M
    __hip_bfloat16* gb    = zb    + (size_t)NTOK * DINNER;        // 4M
    __hip_bfloat16* wbufb = gb    + (size_t)NTOK * DINNER;        // 4M
    __hip_bfloat16* W1b   = wbufb + (size_t)NTOK * DINNER;        // 0.5M
    __hip_bfloat16* w2T   = W1b   + (size_t)DMODEL * DINNER;      // 0.5M
    __hip_bfloat16* convT = w2T   + (size_t)DINNER * DMODEL;      // 4M
    __hip_bfloat16* wdelT = convT + (size_t)4 * DINNER * DINNER;  // 1088 x 1024
    __hip_bfloat16* woutT = wdelT + (size_t)1088 * DINNER;        // 0.5M
    __hip_bfloat16* FT    = woutT + (size_t)DINNER * DMODEL;      // 2M (1024 x 2048)
    __hip_bfloat16* zpage = FT    + (size_t)DINNER * 2048;        // 8K elems
    __hip_bfloat16* P0    = zpage + 8192;                         // 4M elems
    __hip_bfloat16* P1    = P0    + (size_t)NTOK * DINNER;        // 4M elems

    // one-launch prep: cvts + transposes + bcw + zero fills
    prep_k<<<8872, 256, 0, stream>>>(x, w_in, conv_k, w_del, w_B, w_C, w_out,
                                     xb, W1b, w2T, convT, wdelT, woutT, zpage);

    // fused conv weights: FT[o][tap*512 + dm] = (W1 @ K_tap)[dm][o], row stride 2048
    mgemm<4, 64, 64><<<dim3(DMODEL / 64, DINNER / 64, 4), 256, 0, stream>>>(
        convT, 4 * DINNER, W1b, DINNER, nullptr, FT, nullptr, 4 * DMODEL, DINNER,
        nullptr, nullptr, nullptr, 0, zpage, nullptr, nullptr, nullptr, nullptr, nullptr);
    // fused conv(split-K2)+z: bn<1024 -> P0 (taps 0-1); <2048 -> P1 (taps 2-3);
    //                         else -> zb (K=512). grid 48x32=1536 (%8 ok)
    mgemm<0, 128, 64><<<dim3(48, NTOK / 128), 256, 0, stream>>>(
        xb, DMODEL, FT, 4 * DMODEL, nullptr, P0, zb, DINNER, 1024,
        nullptr, nullptr, w2T, DMODEL, zpage, nullptr, nullptr, nullptr, nullptr, P1);
    // combine halves: xcb = bf16(silu(P0+P1+conv_b))
    combine_k<<<NTOK * DINNER / 1024, 256, 0, stream>>>(P0, P1, conv_b, xcb);
    // delta + B/C fused: N=1088, tile 64x64, grid (17,64)=1088 blocks (%8 ok)
    mgemm<2, 64, 64><<<dim3(1088 / 64, NTOK / 64), 256, 0, stream>>>(
        xcb, DINNER, wdelT, DINNER, nullptr, wbufb, nullptr, DINNER, DINNER,
        b_del, xcb, nullptr, 0, zpage, b_B, b_C, Bm, Cm, nullptr);
    // scan
    chunkS_k<<<dim3(2 * NCHUNK, DINNER / 128), 256, 0, stream>>>(wbufb, Bm, S);
    hpre_k<<<dim3(2 * DINNER * DSTATE / 256), 256, 0, stream>>>(S, Hb);
    intra_k<<<dim3(2 * NCHUNK, DINNER / 64), 256, 0, stream>>>(wbufb, Bm, Cm, Hb, zb, gb);
    // out = g @ w_out  (tile 64x64, grid (8,64) = 512 blocks, 16 KB LDS)
    mgemm<3, 64, 64><<<dim3(DMODEL / 64, NTOK / 64), 256, 0, stream>>>(
        gb, DINNER, woutT, DINNER, out, nullptr, nullptr, DMODEL, DINNER,
        nullptr, nullptr, nullptr, 0, zpage, nullptr, nullptr, nullptr, nullptr, nullptr);
}